// Round 4
// baseline (71.643 us; speedup 1.0000x reference)
//
#include <hip/hip_runtime.h>
#include <stdint.h>

#define NROWS 8192
#define DDIM 256
#define NPIDS 5532
#define NCQ 5000
#define LCOLS 10532            // NPIDS + NCQ
#define IGNORE_IDX 5554
#define NT 83                  // ceil(10532/128)
#define LPAD (NT * 128)        // 10624
#define NSPLIT 6
#define NPARTS (NSPLIT * 2)    // 12 partial slots per row
#define PADCOLS (LPAD - LCOLS) // 92, each contributes exp2(0)=1 exactly
#define OIM_SCALE 30.0f
#define LOG2E 1.4426950408889634f
#define LN2f 0.6931471805599453f

using f32x4 = __attribute__((ext_vector_type(4))) float;
using bf16x8 = __attribute__((ext_vector_type(8))) __bf16;
using ushort8 = __attribute__((ext_vector_type(8))) unsigned short;
using int4v = __attribute__((ext_vector_type(4))) int;

// ws layout (bytes)
#define WS_INBF 0u             // 8192*256*2   = 4,194,304 (plain bf16)
#define WS_BANK 4194304u       // 10624*256*2  = 5,439,488 (tiled, rse-scaled)
#define WS_PARTS 9633792u      // 12*8192*4    = 393,216
#define WS_RLOGIT 10027008u    // 8192*4       = 32,768
#define WS_BLK 10059776u       // 32*2*4       = 256
#define WS_NEED 10060032u

__device__ __forceinline__ unsigned short f2bf(float f) {
  union { float f; uint32_t u; } v; v.f = f;
  uint32_t u = v.u;
  uint32_t r = (u + 0x7FFFu + ((u >> 16) & 1u)) >> 16;  // RNE
  return (unsigned short)r;
}

__device__ __forceinline__ void async16(const void* g, void* l) {
  __builtin_amdgcn_global_load_lds(
      (const __attribute__((address_space(1))) uint32_t*)g,
      (__attribute__((address_space(3))) uint32_t*)l, 16, 0, 0);
}

// ---------------------------------------------------------------------------
// prep: inputs -> plain bf16 [row][k].
// bank (lut||cq, zero pad) -> bf16, row j scaled by 30*rel[j]*log2e BEFORE
// quantization, stored TILED: [tile t][kstep kk][row 0..127][granule 0..3],
// granule g stored at slot g ^ ((row>>1)&3) (bank-quad spread for ds_read);
// byte(t,kk,row,g) = t*65536 + kk*8192 + row*64 + (g^((row>>1)&3))*16.
// A LINEAR global_load_lds of one 8KB [kk] chunk lands ready-to-read.
// ---------------------------------------------------------------------------
__global__ void prep_kernel(const float* __restrict__ inputs,
                            const float* __restrict__ lut,
                            const float* __restrict__ cq,
                            const float* __restrict__ rel,
                            unsigned short* __restrict__ in_bf,
                            unsigned short* __restrict__ bank2) {
  const int GIN = NROWS * (DDIM / 8);   // 262144 granules
  const int GBK = LPAD * (DDIM / 8);    // 339968 granules
  const int total = GIN + GBK;
  for (int g = blockIdx.x * blockDim.x + threadIdx.x; g < total;
       g += gridDim.x * blockDim.x) {
    const float* src = nullptr;
    unsigned short* dst;
    float scale = 1.0f;
    bool zero = false;
    if (g < GIN) {
      const int r = g >> 5, c8 = g & 31;
      src = inputs + r * DDIM + c8 * 8;
      dst = in_bf + r * DDIM + c8 * 8;
    } else {
      const int base = g - GIN;
      const int R = base >> 5, c8 = base & 31;    // bank row, source granule
      const int t = R >> 7, row = R & 127;
      const int kk = c8 >> 2, gr = c8 & 3;
      const int gs = gr ^ ((row >> 1) & 3);       // bank-quad swizzle
      dst = bank2 + (size_t)t * 32768 + kk * 4096 + row * 32 + gs * 8;
      if (R < NPIDS) src = lut + R * DDIM + c8 * 8;
      else if (R < LCOLS) src = cq + (R - NPIDS) * DDIM + c8 * 8;
      else zero = true;
      if (!zero) scale = OIM_SCALE * LOG2E * rel[R];
    }
    ushort8 o = {0, 0, 0, 0, 0, 0, 0, 0};
    if (!zero) {
      const f32x4* s4 = (const f32x4*)src;
      f32x4 v0 = s4[0], v1 = s4[1];
      o[0] = f2bf(v0[0] * scale); o[1] = f2bf(v0[1] * scale);
      o[2] = f2bf(v0[2] * scale); o[3] = f2bf(v0[3] * scale);
      o[4] = f2bf(v1[0] * scale); o[5] = f2bf(v1[1] * scale);
      o[6] = f2bf(v1[2] * scale); o[7] = f2bf(v1[3] * scale);
    }
    *(ushort8*)dst = o;
  }
}

// ---------------------------------------------------------------------------
// main: fused GEMM + sum-of-exp + label-logit capture.
// 768 blocks = 3/CU perfectly packed; 256 threads = 4 waves (2x2 over a
// 64x128 tile, wave tile 32x64). sp = bid%6 column split (14 or 13 tiles).
// A: 64 VGPR register fragments, loaded once (issued FIRST for vmcnt order).
// B: 4 x 8KB LDS ring (1 kstep each), staged depth-3 via global_load_lds;
//    steady-state `s_waitcnt vmcnt(4)` + raw s_barrier per phase.
// B pre-scaled by rse -> epilogue is exp2(acc)+add; the lane owning
// (row,label[row]) also writes acc (the label logit, log2 units) to rowlogit.
// ---------------------------------------------------------------------------
__global__ __launch_bounds__(256, 3) void oim_main_kernel(
    const unsigned short* __restrict__ in_bf,
    const unsigned short* __restrict__ bank2,
    const int* __restrict__ label,
    float* __restrict__ parts,
    float* __restrict__ rowlogit) {
  __shared__ char Bs[32768];  // 4 x 8KB ring
  const int tid = threadIdx.x;
  const int lane = tid & 63;
  const int wv = tid >> 6;
  const int wrow = wv >> 1;   // 0..1
  const int wcol = wv & 1;    // 0..1
  const int ql = lane & 15;
  const int h = lane >> 4;    // 0..3

  const int bid = blockIdx.x;
  const int sp = bid % NSPLIT;
  const int bm = bid / NSPLIT;
  const int ntiles = (sp < 5) ? 14 : 13;
  const int NQ = ntiles * 8;

  // ---- A fragments -> registers, issued FIRST (oldest vmem ops) ----
  bf16x8 aR[2][8];
  {
    const unsigned short* ab =
        in_bf + ((size_t)(bm * 64 + wrow * 32 + ql) * DDIM + h * 8);
#pragma unroll
    for (int mi = 0; mi < 2; ++mi)
#pragma unroll
      for (int kk = 0; kk < 8; ++kk)
        aR[mi][kk] = *(const bf16x8*)(ab + mi * 16 * DDIM + kk * 32);
  }
  // labels for this lane's 8 output rows
  const int rowb = bm * 64 + wrow * 32 + h * 4;
  int4v lbl[2];
#pragma unroll
  for (int mi = 0; mi < 2; ++mi)
    lbl[mi] = *(const int4v*)(label + rowb + mi * 16);

  asm volatile("" ::: "memory");  // pin: A-loads before B staging in vmcnt order

  // ---- stage prologue: phases 0,1,2 (tile sp, ksteps 0..2) ----
  const char* bank0 = (const char*)bank2;
  const char* cb = bank0 + (size_t)sp * 65536;  // current tile base
  const int lin = tid * 16;
#pragma unroll
  for (int P = 0; P < 3; ++P) {
#pragma unroll
    for (int j = 0; j < 2; ++j)
      async16(cb + P * 8192 + lin + j * 4096, Bs + P * 8192 + lin + j * 4096);
  }

  // B LDS read base: addr = pB + (q&3)*8192 + ni*1024 (immediate-foldable)
  const char* pB =
      Bs + (wcol * 64 + ql) * 64 + ((h ^ ((ql >> 1) & 3)) << 4);

  const f32x4 vzero = {0.f, 0.f, 0.f, 0.f};
  f32x4 acc[2][4];
  float se[2][4];
#pragma unroll
  for (int a = 0; a < 2; ++a)
#pragma unroll
    for (int b = 0; b < 4; ++b) se[a][b] = 0.f;

  for (int i = 0; i < ntiles; ++i) {
    const int t = sp + i * NSPLIT;
#pragma unroll
    for (int q = 0; q < 8; ++q) {
      const int Q = i * 8 + q;
      const int ahead = NQ - 1 - Q;
      // counted waits: stage(Q) = 2 wave-ops; stages Q+1,Q+2 may be in flight
      if (ahead >= 2)      asm volatile("s_waitcnt vmcnt(4)" ::: "memory");
      else if (ahead == 1) asm volatile("s_waitcnt vmcnt(2)" ::: "memory");
      else                 asm volatile("s_waitcnt vmcnt(0)" ::: "memory");
      asm volatile("s_barrier" ::: "memory");  // raw: no vmcnt(0) drain
      if (Q + 3 < NQ) {  // stage phase Q+3 into buffer (Q+3)&3
        const char* sb =
            ((q + 3) < 8 ? cb : cb + NSPLIT * 65536) + ((q + 3) & 7) * 8192;
        char* db = Bs + ((q + 3) & 3) * 8192 + lin;
        async16(sb + lin, db);
        async16(sb + lin + 4096, db + 4096);
      }
      // compute kstep q from buffer q&3
      bf16x8 bF[4];
#pragma unroll
      for (int ni = 0; ni < 4; ++ni)
        bF[ni] = *(const bf16x8*)(pB + (q & 3) * 8192 + ni * 1024);
      __builtin_amdgcn_s_setprio(1);
#pragma unroll
      for (int mi = 0; mi < 2; ++mi)
#pragma unroll
        for (int ni = 0; ni < 4; ++ni)
          acc[mi][ni] = __builtin_amdgcn_mfma_f32_16x16x32_bf16(
              aR[mi][q], bF[ni], (q == 0) ? vzero : acc[mi][ni], 0, 0, 0);
      __builtin_amdgcn_s_setprio(0);
    }
    // tile epilogue: exp2 accumulate + label-logit capture (log2 units)
    const int colb = t * 128 + wcol * 64 + ql;
#pragma unroll
    for (int ni = 0; ni < 4; ++ni) {
      const int col = colb + ni * 16;
#pragma unroll
      for (int mi = 0; mi < 2; ++mi)
#pragma unroll
        for (int r = 0; r < 4; ++r) {
          const float v = acc[mi][ni][r];
          se[mi][r] += __builtin_amdgcn_exp2f(v);
          if (lbl[mi][r] == col) rowlogit[rowb + mi * 16 + r] = v;
        }
    }
    cb += (size_t)NSPLIT * 65536;
  }

  // reduce across the 16 column-lanes (ql) of each row group
#pragma unroll
  for (int mi = 0; mi < 2; ++mi)
#pragma unroll
    for (int r = 0; r < 4; ++r) {
      float v = se[mi][r];
      v += __shfl_xor(v, 1);
      v += __shfl_xor(v, 2);
      v += __shfl_xor(v, 4);
      v += __shfl_xor(v, 8);
      se[mi][r] = v;
    }
  if (ql == 0) {
    const int part = sp * 2 + wcol;  // deterministic partial slot
#pragma unroll
    for (int mi = 0; mi < 2; ++mi) {
      f32x4 o = {se[mi][0], se[mi][1], se[mi][2], se[mi][3]};
      *(f32x4*)(parts + (size_t)part * NROWS + rowb + mi * 16) = o;
    }
  }
}

// ---------------------------------------------------------------------------
// reduce1: 32 blocks x 256 threads, one row per thread.
// tot = sum(parts) - PADCOLS; s = ln2*(log2(tot) - rowlogit) for valid rows.
// ---------------------------------------------------------------------------
__global__ void reduce1_kernel(const float* __restrict__ parts,
                               const float* __restrict__ rowlogit,
                               const int* __restrict__ label,
                               float* __restrict__ blk) {
  const int r = blockIdx.x * 256 + threadIdx.x;
  float s = 0.0f, c = 0.0f;
  if (label[r] != IGNORE_IDX) {
    float tot = 0.0f;
#pragma unroll
    for (int p = 0; p < NPARTS; ++p) tot += parts[p * NROWS + r];
    tot -= (float)PADCOLS;
    s = LN2f * (__builtin_log2f(tot) - rowlogit[r]);
    c = 1.0f;
  }
#pragma unroll
  for (int m = 1; m < 64; m <<= 1) {
    s += __shfl_xor(s, m);
    c += __shfl_xor(c, m);
  }
  __shared__ float ss[4], sc[4];
  const int wv = threadIdx.x >> 6, lane = threadIdx.x & 63;
  if (lane == 0) { ss[wv] = s; sc[wv] = c; }
  __syncthreads();
  if (threadIdx.x == 0) {
    blk[blockIdx.x * 2 + 0] = ss[0] + ss[1] + ss[2] + ss[3];
    blk[blockIdx.x * 2 + 1] = sc[0] + sc[1] + sc[2] + sc[3];
  }
}

__global__ void reduce2_kernel(const float* __restrict__ blk,
                               float* __restrict__ out) {
  const int lane = threadIdx.x;
  float s = (lane < 32) ? blk[lane * 2 + 0] : 0.0f;
  float c = (lane < 32) ? blk[lane * 2 + 1] : 0.0f;
#pragma unroll
  for (int m = 1; m < 32; m <<= 1) {
    s += __shfl_xor(s, m);
    c += __shfl_xor(c, m);
  }
  if (lane == 0) out[0] = s / fmaxf(c, 1.0f);
}

extern "C" void kernel_launch(void* const* d_in, const int* in_sizes, int n_in,
                              void* d_out, int out_size, void* d_ws,
                              size_t ws_size, hipStream_t stream) {
  const float* inputs = (const float*)d_in[0];
  const int* label = (const int*)d_in[1];
  // d_in[2] = ious (unused by the reference loss)
  const float* lut = (const float*)d_in[3];
  const float* cq = (const float*)d_in[4];
  const float* rel = (const float*)d_in[5];
  float* out = (float*)d_out;
  char* ws = (char*)d_ws;
  if (ws_size < WS_NEED) return;

  unsigned short* in_bf = (unsigned short*)(ws + WS_INBF);
  unsigned short* bank2 = (unsigned short*)(ws + WS_BANK);
  float* parts = (float*)(ws + WS_PARTS);
  float* rowlogit = (float*)(ws + WS_RLOGIT);
  float* blk = (float*)(ws + WS_BLK);

  prep_kernel<<<dim3(1024), dim3(256), 0, stream>>>(inputs, lut, cq, rel,
                                                    in_bf, bank2);
  oim_main_kernel<<<dim3(128 * NSPLIT), dim3(256), 0, stream>>>(
      in_bf, bank2, label, parts, rowlogit);
  reduce1_kernel<<<dim3(32), dim3(256), 0, stream>>>(parts, rowlogit, label,
                                                     blk);
  reduce2_kernel<<<dim3(1), dim3(64), 0, stream>>>(blk, out);
}